// Round 1
// baseline (973.315 us; speedup 1.0000x reference)
//
#include <hip/hip_runtime.h>
#include <cmath>

// Problem constants (fixed by the reference):
// B=8, DIM=128, T=16, H*W=1024, INNER=256, UP2=512, NH=4, DH=64, K=4
// Bx = 8192 sequences, S = 16.

static __device__ __forceinline__ float dot4(float4 a, float4 b) {
  return a.x*b.x + a.y*b.y + a.z*b.z + a.w*b.w;
}
static __device__ __forceinline__ float siluf(float v) {
  return v / (1.0f + __expf(-v));
}

// ---------------------------------------------------------------------------
// Phase 1: up-projection GEMM. out[m, j] = sum_c x[m, c] * Wup[c, j]
// m = (b, t, hw) with hw contiguous in x; j in [0,512).
// j < 256 -> x_m raw; j >= 256 -> silu(z) stored to sz.
// Block tile: 128 hw x 128 j, 8x8 per thread, K chunks of 32 in LDS.
// ---------------------------------------------------------------------------
__global__ __launch_bounds__(256, 4)
void up_gemm(const float* __restrict__ x, const float* __restrict__ Wup,
             float* __restrict__ xm, float* __restrict__ sz)
{
  __shared__ float sA[32][128];   // [c][hw]
  __shared__ float sW[32][128];   // [c][j]
  const int tid = threadIdx.x;
  const int th  = tid & 15;       // hw sub-tile
  const int tj  = tid >> 4;       // j sub-tile
  const int hw0 = blockIdx.x * 128;
  const int j0  = blockIdx.y * 128;
  const int bt  = blockIdx.z;     // b*16 + t
  const int b   = bt >> 4;
  const int t   = bt & 15;

  float acc[8][8];                // [hh][jj]
  #pragma unroll
  for (int i = 0; i < 8; ++i)
    #pragma unroll
    for (int k = 0; k < 8; ++k) acc[i][k] = 0.0f;

  for (int c0 = 0; c0 < 128; c0 += 32) {
    #pragma unroll
    for (int r = 0; r < 4; ++r) {
      const int lin = r*256 + tid;          // 1024 float4 units
      const int row = lin >> 5;             // 0..31 (c)
      const int cv  = (lin & 31) * 4;       // 0..124
      *(float4*)&sA[row][cv] =
          *(const float4*)&x[((b*128 + c0 + row)*16 + t)*1024 + hw0 + cv];
      *(float4*)&sW[row][cv] =
          *(const float4*)&Wup[(c0 + row)*512 + j0 + cv];
    }
    __syncthreads();
    #pragma unroll 4
    for (int cc = 0; cc < 32; ++cc) {
      const float4 a0 = *(const float4*)&sA[cc][th*4];
      const float4 a1 = *(const float4*)&sA[cc][64 + th*4];
      const float4 w0 = *(const float4*)&sW[cc][tj*4];
      const float4 w1 = *(const float4*)&sW[cc][64 + tj*4];
      const float av[8] = {a0.x,a0.y,a0.z,a0.w,a1.x,a1.y,a1.z,a1.w};
      const float wv[8] = {w0.x,w0.y,w0.z,w0.w,w1.x,w1.y,w1.z,w1.w};
      #pragma unroll
      for (int hh = 0; hh < 8; ++hh)
        #pragma unroll
        for (int jj = 0; jj < 8; ++jj)
          acc[hh][jj] += av[hh] * wv[jj];
    }
    __syncthreads();
  }

  const bool is_z = (j0 >= 256);
  float* dst = is_z ? sz : xm;
  const int jb = j0 & 255;
  const int rowbase = bt * 1024 + hw0;
  #pragma unroll
  for (int hh = 0; hh < 8; ++hh) {
    const int hwv = (hh < 4) ? (th*4 + hh) : (64 + th*4 + hh - 4);
    float o[8];
    #pragma unroll
    for (int jj = 0; jj < 8; ++jj) o[jj] = acc[hh][jj];
    if (is_z) {
      #pragma unroll
      for (int jj = 0; jj < 8; ++jj) o[jj] = siluf(o[jj]);
    }
    float* p = &dst[(rowbase + hwv)*256 + jb + tj*4];
    *(float4*)p        = make_float4(o[0], o[1], o[2], o[3]);
    *(float4*)(p + 64) = make_float4(o[4], o[5], o[6], o[7]);
  }
}

// ---------------------------------------------------------------------------
// Phase 2: per-sequence fused conv + headwise qkv + gates + mLSTM + LN + skip.
// One block (256 threads) per sequence (b, hw). h_state overwrites xm buffer.
// ---------------------------------------------------------------------------
#define LROW 268   // padded LDS row (268 % 32 == 12 -> kills 4-way conflicts)

__global__ __launch_bounds__(256, 2)
void seq_kernel(const float* xm_ws,               // aliases h_ws (no restrict)
                const float* __restrict__ sz_ws,
                float* h_ws,
                const float* __restrict__ conv_w, const float* __restrict__ conv_b,
                const float* __restrict__ Wq, const float* __restrict__ Wk,
                const float* __restrict__ Wv,
                const float* __restrict__ igw, const float* __restrict__ igb,
                const float* __restrict__ fgw, const float* __restrict__ fgb,
                const float* __restrict__ lnw, const float* __restrict__ skipw)
{
  __shared__ float s_xc[16][LROW];
  __shared__ float s_q [16][LROW];
  __shared__ float s_k [16][LROW];
  __shared__ float s_v [16][LROW];
  __shared__ float s_C [4][16][17];
  __shared__ float s_gp[16][4][4][2];
  __shared__ float s_ig[16][4];
  __shared__ float s_lf[16][4];
  __shared__ float s_lfc[17][4];

  const int tid  = threadIdx.x;
  const int seq  = blockIdx.x;                    // b*1024 + hw
  const int rbase = (seq >> 10) * 16384 + (seq & 1023);  // row(t) = rbase + t*1024

  const int j = tid;
  const float4 wq = *(const float4*)&Wq[j*4];     // Wq[n][o][0..3], n=j/4, o=j%4
  const float4 wk = *(const float4*)&Wk[j*4];
  const float4 wv = *(const float4*)&Wv[j*4];
  const float cw0 = conv_w[j],     cw1 = conv_w[256+j];
  const float cw2 = conv_w[512+j], cw3 = conv_w[768+j];
  const float cb  = conv_b[j];

  // Pass 1: load x_m rows; causal conv (zero left-pad) + silu -> s_xc; raw -> s_v
  float p3 = 0.f, p2 = 0.f, p1 = 0.f;
  #pragma unroll
  for (int t = 0; t < 16; ++t) {
    const float m = xm_ws[(rbase + t*1024)*256 + j];
    const float pre = cw0*p3 + cw1*p2 + cw2*p1 + cw3*m + cb;
    s_xc[t][j] = siluf(pre);
    s_v [t][j] = m;                                // raw x_m (temp)
    p3 = p2; p2 = p1; p1 = m;
  }
  __syncthreads();

  // Pass 2: headwise q,k from xc; v from raw x_m (held in regs, stored after sync)
  const int n4 = j & ~3;
  float vv[16];
  #pragma unroll
  for (int t = 0; t < 16; ++t) {
    const float4 xc4 = *(const float4*)&s_xc[t][n4];
    const float4 xm4 = *(const float4*)&s_v [t][n4];
    s_q[t][j] = dot4(wq, xc4);
    s_k[t][j] = dot4(wk, xc4);
    vv[t]     = dot4(wv, xm4);
  }
  __syncthreads();
  #pragma unroll
  for (int t = 0; t < 16; ++t) s_v[t][j] = vv[t];
  __syncthreads();

  // Gates: ig/fg[t][h] = [q|k|v] . w[:,h] + b ; thread = (t, h, p), p strides 4
  {
    const int gt = tid >> 4, gh = (tid >> 2) & 3, gp = tid & 3;
    float pig = 0.f, pfg = 0.f;
    for (int m = 0; m < 192; ++m) {
      const int jj = m*4 + gp;
      float y;
      if (jj < 256)      y = s_q[gt][jj];
      else if (jj < 512) y = s_k[gt][jj-256];
      else               y = s_v[gt][jj-512];
      pig = fmaf(y, igw[jj*4 + gh], pig);
      pfg = fmaf(y, fgw[jj*4 + gh], pfg);
    }
    s_gp[gt][gh][gp][0] = pig;
    s_gp[gt][gh][gp][1] = pfg;
  }
  __syncthreads();
  if (tid < 64) {
    const int t = tid >> 2, h = tid & 3;
    const float ig = s_gp[t][h][0][0]+s_gp[t][h][1][0]+s_gp[t][h][2][0]+s_gp[t][h][3][0] + igb[h];
    const float fg = s_gp[t][h][0][1]+s_gp[t][h][1][1]+s_gp[t][h][2][1]+s_gp[t][h][3][1] + fgb[h];
    s_ig[t][h] = ig;
    s_lf[t][h] = fminf(fg, 0.f) - log1pf(expf(-fabsf(fg)));  // log_sigmoid
  }
  __syncthreads();
  if (tid < 4) {
    float run = 0.f;
    s_lfc[0][tid] = 0.f;
    for (int t = 0; t < 16; ++t) { run += s_lf[t][tid]; s_lfc[t+1][tid] = run; }
  }
  __syncthreads();

  // mLSTM: wave per head. lane = (sI = lane/4, g4 = lane%4)
  const int h    = tid >> 6;
  const int lane = tid & 63;
  const int sI   = lane >> 2;
  const int g4   = lane & 3;
  const int hb   = h * 64;

  {
    // qk[s][t] for t in {g4*4+u}
    float qk[4] = {0.f, 0.f, 0.f, 0.f};
    #pragma unroll 4
    for (int d4 = 0; d4 < 16; ++d4) {
      const float4 qv = *(const float4*)&s_q[sI][hb + d4*4];
      #pragma unroll
      for (int u = 0; u < 4; ++u) {
        const float4 kv = *(const float4*)&s_k[g4*4 + u][hb + d4*4];
        qk[u] += dot4(qv, kv);
      }
    }
    const float lfs = s_lfc[sI + 1][h];
    float ld[4];
    float mloc = -INFINITY;
    #pragma unroll
    for (int u = 0; u < 4; ++u) {
      const int t = g4*4 + u;
      ld[u] = (t <= sI) ? (lfs - s_lfc[t+1][h] + s_ig[t][h]) : -INFINITY;
      mloc = fmaxf(mloc, ld[u]);
    }
    mloc = fmaxf(mloc, __shfl_xor(mloc, 1));   // row max over the 4 t-group lanes
    mloc = fmaxf(mloc, __shfl_xor(mloc, 2));
    float cs[4];
    float rsum = 0.f;
    #pragma unroll
    for (int u = 0; u < 4; ++u) {
      const int t = g4*4 + u;
      float cv = 0.f;
      if (t <= sI) cv = (qk[u] * 0.125f) * __expf(ld[u] - mloc);  // /sqrt(64)
      cs[u] = cv;
      rsum += cv;
    }
    rsum += __shfl_xor(rsum, 1);
    rsum += __shfl_xor(rsum, 2);
    const float denom = fmaxf(fabsf(rsum), __expf(-mloc)) + 1e-6f;
    const float inv = 1.f / denom;
    #pragma unroll
    for (int u = 0; u < 4; ++u) s_C[h][sI][g4*4 + u] = cs[u] * inv;
  }
  __syncthreads();

  // ht[s][d] = sum_t Cn[s][t] * v[t][d]; lane handles d in [g4*16, g4*16+16)
  float o[16];
  #pragma unroll
  for (int i = 0; i < 16; ++i) o[i] = 0.f;
  #pragma unroll 4
  for (int t = 0; t < 16; ++t) {
    const float c = (t <= sI) ? s_C[h][sI][t] : 0.f;
    #pragma unroll
    for (int dd = 0; dd < 4; ++dd) {
      const float4 v4 = *(const float4*)&s_v[t][hb + g4*16 + dd*4];
      o[dd*4+0] += c * v4.x;
      o[dd*4+1] += c * v4.y;
      o[dd*4+2] += c * v4.z;
      o[dd*4+3] += c * v4.w;
    }
  }
  // head LayerNorm over DH=64 (4 lanes per s)
  float sum = 0.f;
  #pragma unroll
  for (int i = 0; i < 16; ++i) sum += o[i];
  sum += __shfl_xor(sum, 1);
  sum += __shfl_xor(sum, 2);
  const float mu = sum * (1.f/64.f);
  float sq = 0.f;
  #pragma unroll
  for (int i = 0; i < 16; ++i) { const float d = o[i] - mu; sq += d*d; }
  sq += __shfl_xor(sq, 1);
  sq += __shfl_xor(sq, 2);
  const float rstd = rsqrtf(sq * (1.f/64.f) + 1e-5f);

  // h_state = (hn + skip*xc) * silu(z); write over xm buffer
  #pragma unroll
  for (int dd = 0; dd < 4; ++dd) {
    const int jj = hb + g4*16 + dd*4;
    const float4 ln4 = *(const float4*)&lnw[jj];
    const float4 sk4 = *(const float4*)&skipw[jj];
    const float4 xc4 = *(const float4*)&s_xc[sI][jj];
    const int off = (rbase + sI*1024)*256 + jj;
    const float4 sz4 = *(const float4*)&sz_ws[off];
    float4 r;
    r.x = ((o[dd*4+0]-mu)*rstd*ln4.x + sk4.x*xc4.x) * sz4.x;
    r.y = ((o[dd*4+1]-mu)*rstd*ln4.y + sk4.y*xc4.y) * sz4.y;
    r.z = ((o[dd*4+2]-mu)*rstd*ln4.z + sk4.z*xc4.z) * sz4.z;
    r.w = ((o[dd*4+3]-mu)*rstd*ln4.w + sk4.w*xc4.w) * sz4.w;
    *(float4*)&h_ws[off] = r;
  }
}

// ---------------------------------------------------------------------------
// Phase 3: down-projection GEMM + transpose-store.
// out[b][c][t][hw] = sum_j h[bt][hw][j] * Wd[j][c]
// ---------------------------------------------------------------------------
__global__ __launch_bounds__(256, 4)
void down_gemm(const float* __restrict__ hws, const float* __restrict__ Wd,
               float* __restrict__ out)
{
  __shared__ float sA[32][132];   // [j][hw], padded
  __shared__ float sW[32][128];   // [j][c]
  const int tid = threadIdx.x;
  const int th  = tid & 15;
  const int tj  = tid >> 4;
  const int hw0 = blockIdx.x * 128;
  const int bt  = blockIdx.z;
  const int b   = bt >> 4, t = bt & 15;

  float acc[8][8];                // [hh][cc]
  #pragma unroll
  for (int i = 0; i < 8; ++i)
    #pragma unroll
    for (int k = 0; k < 8; ++k) acc[i][k] = 0.0f;

  const int rowbase = bt * 1024 + hw0;
  for (int k0 = 0; k0 < 256; k0 += 32) {
    #pragma unroll
    for (int r = 0; r < 4; ++r) {               // A tile, transposed into LDS
      const int lin = r*256 + tid;              // hw(128) x j4(8)
      const int hw  = lin >> 3;
      const int j4  = (lin & 7) * 4;
      const float4 v = *(const float4*)&hws[(rowbase + hw)*256 + k0 + j4];
      sA[j4+0][hw] = v.x;
      sA[j4+1][hw] = v.y;
      sA[j4+2][hw] = v.z;
      sA[j4+3][hw] = v.w;
    }
    #pragma unroll
    for (int r = 0; r < 4; ++r) {               // W tile
      const int lin = r*256 + tid;
      const int row = lin >> 5;
      const int cv  = (lin & 31) * 4;
      *(float4*)&sW[row][cv] = *(const float4*)&Wd[(k0 + row)*128 + cv];
    }
    __syncthreads();
    #pragma unroll 4
    for (int kk = 0; kk < 32; ++kk) {
      const float4 a0 = *(const float4*)&sA[kk][th*4];
      const float4 a1 = *(const float4*)&sA[kk][64 + th*4];
      const float4 w0 = *(const float4*)&sW[kk][tj*4];
      const float4 w1 = *(const float4*)&sW[kk][64 + tj*4];
      const float av[8] = {a0.x,a0.y,a0.z,a0.w,a1.x,a1.y,a1.z,a1.w};
      const float wv[8] = {w0.x,w0.y,w0.z,w0.w,w1.x,w1.y,w1.z,w1.w};
      #pragma unroll
      for (int hh = 0; hh < 8; ++hh)
        #pragma unroll
        for (int cc = 0; cc < 8; ++cc)
          acc[hh][cc] += av[hh] * wv[cc];
    }
    __syncthreads();
  }

  #pragma unroll
  for (int jj = 0; jj < 8; ++jj) {
    const int c = (jj < 4) ? (tj*4 + jj) : (64 + tj*4 + jj - 4);
    const float4 v0 = make_float4(acc[0][jj], acc[1][jj], acc[2][jj], acc[3][jj]);
    const float4 v1 = make_float4(acc[4][jj], acc[5][jj], acc[6][jj], acc[7][jj]);
    const int obase = ((b*128 + c)*16 + t)*1024 + hw0;
    *(float4*)&out[obase + th*4]      = v0;
    *(float4*)&out[obase + 64 + th*4] = v1;
  }
}

// ---------------------------------------------------------------------------
extern "C" void kernel_launch(void* const* d_in, const int* in_sizes, int n_in,
                              void* d_out, int out_size, void* d_ws, size_t ws_size,
                              hipStream_t stream)
{
  const float* x      = (const float*)d_in[0];
  const float* Wup    = (const float*)d_in[1];
  const float* conv_w = (const float*)d_in[2];
  const float* conv_b = (const float*)d_in[3];
  const float* Wq     = (const float*)d_in[4];
  const float* Wk     = (const float*)d_in[5];
  const float* Wv     = (const float*)d_in[6];
  const float* igw    = (const float*)d_in[7];
  const float* igb    = (const float*)d_in[8];
  const float* fgw    = (const float*)d_in[9];
  const float* fgb    = (const float*)d_in[10];
  const float* lnw    = (const float*)d_in[11];
  const float* skipw  = (const float*)d_in[12];
  const float* Wd     = (const float*)d_in[13];
  float* out = (float*)d_out;

  // Workspace: xm [8192*16, 256] f32 (128 MB, reused for h_state), sz same (128 MB).
  float* xm = (float*)d_ws;
  float* sz = xm + 33554432;

  up_gemm<<<dim3(8, 4, 128), 256, 0, stream>>>(x, Wup, xm, sz);
  seq_kernel<<<8192, 256, 0, stream>>>(xm, sz, xm,
                                       conv_w, conv_b, Wq, Wk, Wv,
                                       igw, igb, fgw, fgb, lnw, skipw);
  down_gemm<<<dim3(8, 1, 128), 256, 0, stream>>>(xm, Wd, out);
}

// Round 2
// 666.169 us; speedup vs baseline: 1.4611x; 1.4611x over previous
//
#include <hip/hip_runtime.h>
#include <cmath>

// Problem constants: B=8, DIM=128, T=16, H*W=1024, INNER=256, UP2=512,
// NH=4, DH=64, K=4, Bx=8192 sequences, S=16.

static __device__ __forceinline__ float dot4(float4 a, float4 b) {
  return a.x*b.x + a.y*b.y + a.z*b.z + a.w*b.w;
}
static __device__ __forceinline__ float siluf(float v) {
  return v / (1.0f + __expf(-v));
}
static __device__ __forceinline__ float logsigf(float v) {
  return fminf(v, 0.f) - log1pf(__expf(-fabsf(v)));
}
static __device__ __forceinline__ float sel4(float4 w, int idx) {
  float r = w.x;
  r = (idx == 1) ? w.y : r;
  r = (idx == 2) ? w.z : r;
  r = (idx == 3) ? w.w : r;
  return r;
}

// ---------------------------------------------------------------------------
// Phase 1: up-projection GEMM (unchanged from R1).
// ---------------------------------------------------------------------------
__global__ __launch_bounds__(256, 4)
void up_gemm(const float* __restrict__ x, const float* __restrict__ Wup,
             float* __restrict__ xm, float* __restrict__ sz)
{
  __shared__ float sA[32][128];
  __shared__ float sW[32][128];
  const int tid = threadIdx.x;
  const int th  = tid & 15;
  const int tj  = tid >> 4;
  const int hw0 = blockIdx.x * 128;
  const int j0  = blockIdx.y * 128;
  const int bt  = blockIdx.z;
  const int b   = bt >> 4;
  const int t   = bt & 15;

  float acc[8][8];
  #pragma unroll
  for (int i = 0; i < 8; ++i)
    #pragma unroll
    for (int k = 0; k < 8; ++k) acc[i][k] = 0.0f;

  for (int c0 = 0; c0 < 128; c0 += 32) {
    #pragma unroll
    for (int r = 0; r < 4; ++r) {
      const int lin = r*256 + tid;
      const int row = lin >> 5;
      const int cv  = (lin & 31) * 4;
      *(float4*)&sA[row][cv] =
          *(const float4*)&x[((b*128 + c0 + row)*16 + t)*1024 + hw0 + cv];
      *(float4*)&sW[row][cv] =
          *(const float4*)&Wup[(c0 + row)*512 + j0 + cv];
    }
    __syncthreads();
    #pragma unroll 4
    for (int cc = 0; cc < 32; ++cc) {
      const float4 a0 = *(const float4*)&sA[cc][th*4];
      const float4 a1 = *(const float4*)&sA[cc][64 + th*4];
      const float4 w0 = *(const float4*)&sW[cc][tj*4];
      const float4 w1 = *(const float4*)&sW[cc][64 + tj*4];
      const float av[8] = {a0.x,a0.y,a0.z,a0.w,a1.x,a1.y,a1.z,a1.w};
      const float wv[8] = {w0.x,w0.y,w0.z,w0.w,w1.x,w1.y,w1.z,w1.w};
      #pragma unroll
      for (int hh = 0; hh < 8; ++hh)
        #pragma unroll
        for (int jj = 0; jj < 8; ++jj)
          acc[hh][jj] += av[hh] * wv[jj];
    }
    __syncthreads();
  }

  const bool is_z = (j0 >= 256);
  float* dst = is_z ? sz : xm;
  const int jb = j0 & 255;
  const int rowbase = bt * 1024 + hw0;
  #pragma unroll
  for (int hh = 0; hh < 8; ++hh) {
    const int hwv = (hh < 4) ? (th*4 + hh) : (64 + th*4 + hh - 4);
    float o[8];
    #pragma unroll
    for (int jj = 0; jj < 8; ++jj) o[jj] = acc[hh][jj];
    if (is_z) {
      #pragma unroll
      for (int jj = 0; jj < 8; ++jj) o[jj] = siluf(o[jj]);
    }
    float* p = &dst[(rowbase + hwv)*256 + jb + tj*4];
    *(float4*)p        = make_float4(o[0], o[1], o[2], o[3]);
    *(float4*)(p + 64) = make_float4(o[4], o[5], o[6], o[7]);
  }
}

// ---------------------------------------------------------------------------
// Phase 2 (rewritten): registers for xc/v, shuffle headwise qkv, vectorized
// gate GEMV, channel-layout PV + LN + epilogue (no transpose).
// LDS: q,k,v [16][264] f32 + small gate arrays = 51.5 KB -> 3 blocks/CU.
// ---------------------------------------------------------------------------
#define QR 264   // row stride in floats; 264%32==8 -> 2-way max (free)

__global__ __launch_bounds__(256, 3)
void seq_kernel(const float* xm_ws,               // aliases h_ws
                const float* __restrict__ sz_ws,
                float* h_ws,
                const float* __restrict__ conv_w, const float* __restrict__ conv_b,
                const float* __restrict__ Wq, const float* __restrict__ Wk,
                const float* __restrict__ Wv,
                const float* __restrict__ igw, const float* __restrict__ igb,
                const float* __restrict__ fgw, const float* __restrict__ fgb,
                const float* __restrict__ lnw, const float* __restrict__ skipw)
{
  __shared__ __align__(16) float s_q[16*QR];   // later aliased as C[4][16][16]
  __shared__ __align__(16) float s_k[16*QR];
  __shared__ __align__(16) float s_v[16*QR];
  __shared__ __align__(16) float s_ig[16*4];   // [t][h]
  __shared__ __align__(16) float s_lf[16*4];   // [t][h]
  __shared__ float s_lfc[17*4];                // [t+1][h]

  const int tid = threadIdx.x;
  const int j   = tid;
  const int l2  = j & 3;
  const int seq = blockIdx.x;
  const int rbase = (seq >> 10) * 16384 + (seq & 1023);  // row(t)=rbase+t*1024

  // --- weights (lane-permuted so shuffled quad values pair correctly) ---
  const float4 wq4 = *(const float4*)&Wq[j*4];
  const float4 wk4 = *(const float4*)&Wk[j*4];
  const float4 wv4 = *(const float4*)&Wv[j*4];
  float wqp[4], wkp[4], wvp[4];
  #pragma unroll
  for (int d = 0; d < 4; ++d) {
    const int idx = l2 ^ d;
    wqp[d] = sel4(wq4, idx);
    wkp[d] = sel4(wk4, idx);
    wvp[d] = sel4(wv4, idx);
  }
  const float cw0 = conv_w[j],     cw1 = conv_w[256+j];
  const float cw2 = conv_w[512+j], cw3 = conv_w[768+j];
  const float cb  = conv_b[j];

  // --- pass 1+2: conv + silu + headwise q,k,v via quad shuffles ---
  float xc[16], vreg[16];
  float p1 = 0.f, p2 = 0.f, p3 = 0.f;
  #pragma unroll
  for (int t = 0; t < 16; ++t) {
    const float m = xm_ws[(rbase + t*1024)*256 + j];
    const float pre = cw0*p3 + cw1*p2 + cw2*p1 + cw3*m + cb;
    const float x = siluf(pre);
    xc[t] = x;
    p3 = p2; p2 = p1; p1 = m;
    const float x1 = __shfl_xor(x, 1), x2 = __shfl_xor(x, 2), x3 = __shfl_xor(x, 3);
    const float m1 = __shfl_xor(m, 1), m2 = __shfl_xor(m, 2), m3 = __shfl_xor(m, 3);
    const float q = x*wqp[0] + x1*wqp[1] + x2*wqp[2] + x3*wqp[3];
    const float k = x*wkp[0] + x1*wkp[1] + x2*wkp[2] + x3*wkp[3];
    const float v = m*wvp[0] + m1*wvp[1] + m2*wvp[2] + m3*wvp[3];
    s_q[t*QR + j] = q;
    s_k[t*QR + j] = k;
    s_v[t*QR + j] = v;
    vreg[t] = v;
  }
  __syncthreads();   // B1

  // --- gates: thread (gt = t, gp = channel phase); float4 weight-row loads ---
  {
    const int gt = tid >> 4, gp = tid & 15;
    float4 aig = make_float4(0.f,0.f,0.f,0.f);
    float4 afg = make_float4(0.f,0.f,0.f,0.f);
    const float* qrow = &s_q[gt*QR];
    const float* krow = &s_k[gt*QR];
    const float* vrow = &s_v[gt*QR];
    #pragma unroll
    for (int m = 0; m < 16; ++m) {
      const int ch = gp + (m << 4);
      const float y = qrow[ch];
      const float4 wi = *(const float4*)&igw[ch*4];
      const float4 wf = *(const float4*)&fgw[ch*4];
      aig.x = fmaf(y, wi.x, aig.x); aig.y = fmaf(y, wi.y, aig.y);
      aig.z = fmaf(y, wi.z, aig.z); aig.w = fmaf(y, wi.w, aig.w);
      afg.x = fmaf(y, wf.x, afg.x); afg.y = fmaf(y, wf.y, afg.y);
      afg.z = fmaf(y, wf.z, afg.z); afg.w = fmaf(y, wf.w, afg.w);
    }
    #pragma unroll
    for (int m = 0; m < 16; ++m) {
      const int ch = gp + (m << 4);
      const float y = krow[ch];
      const float4 wi = *(const float4*)&igw[(256+ch)*4];
      const float4 wf = *(const float4*)&fgw[(256+ch)*4];
      aig.x = fmaf(y, wi.x, aig.x); aig.y = fmaf(y, wi.y, aig.y);
      aig.z = fmaf(y, wi.z, aig.z); aig.w = fmaf(y, wi.w, aig.w);
      afg.x = fmaf(y, wf.x, afg.x); afg.y = fmaf(y, wf.y, afg.y);
      afg.z = fmaf(y, wf.z, afg.z); afg.w = fmaf(y, wf.w, afg.w);
    }
    #pragma unroll
    for (int m = 0; m < 16; ++m) {
      const int ch = gp + (m << 4);
      const float y = vrow[ch];
      const float4 wi = *(const float4*)&igw[(512+ch)*4];
      const float4 wf = *(const float4*)&fgw[(512+ch)*4];
      aig.x = fmaf(y, wi.x, aig.x); aig.y = fmaf(y, wi.y, aig.y);
      aig.z = fmaf(y, wi.z, aig.z); aig.w = fmaf(y, wi.w, aig.w);
      afg.x = fmaf(y, wf.x, afg.x); afg.y = fmaf(y, wf.y, afg.y);
      afg.z = fmaf(y, wf.z, afg.z); afg.w = fmaf(y, wf.w, afg.w);
    }
    #pragma unroll
    for (int off = 1; off < 16; off <<= 1) {
      aig.x += __shfl_xor(aig.x, off); aig.y += __shfl_xor(aig.y, off);
      aig.z += __shfl_xor(aig.z, off); aig.w += __shfl_xor(aig.w, off);
      afg.x += __shfl_xor(afg.x, off); afg.y += __shfl_xor(afg.y, off);
      afg.z += __shfl_xor(afg.z, off); afg.w += __shfl_xor(afg.w, off);
    }
    if (gp == 0) {
      const float4 ib = *(const float4*)&igb[0];
      const float4 fb = *(const float4*)&fgb[0];
      *(float4*)&s_ig[gt*4] = make_float4(aig.x+ib.x, aig.y+ib.y, aig.z+ib.z, aig.w+ib.w);
      *(float4*)&s_lf[gt*4] = make_float4(logsigf(afg.x+fb.x), logsigf(afg.y+fb.y),
                                          logsigf(afg.z+fb.z), logsigf(afg.w+fb.w));
    }
  }
  __syncthreads();   // B2
  if (tid < 4) {
    float run = 0.f;
    s_lfc[tid] = 0.f;
    #pragma unroll
    for (int t = 0; t < 16; ++t) { run += s_lf[t*4 + tid]; s_lfc[(t+1)*4 + tid] = run; }
  }
  __syncthreads();   // B3

  // --- mLSTM scores: wave per head; lane = (sI = lane/4, g4 = lane%4) ---
  const int h    = tid >> 6;
  const int lane = tid & 63;
  const int sI   = lane >> 2;
  const int g4   = lane & 3;
  const int hb   = h * 64;

  float csv[4];
  {
    float qk[4] = {0.f, 0.f, 0.f, 0.f};
    #pragma unroll 4
    for (int d4 = 0; d4 < 16; ++d4) {
      const float4 qv = *(const float4*)&s_q[sI*QR + hb + d4*4];
      #pragma unroll
      for (int u = 0; u < 4; ++u) {
        const float4 kv = *(const float4*)&s_k[(g4*4+u)*QR + hb + d4*4];
        qk[u] += dot4(qv, kv);
      }
    }
    const float lfs = s_lfc[(sI+1)*4 + h];
    float ld[4];
    float mloc = -INFINITY;
    #pragma unroll
    for (int u = 0; u < 4; ++u) {
      const int t = g4*4 + u;
      ld[u] = (t <= sI) ? (lfs - s_lfc[(t+1)*4 + h] + s_ig[t*4 + h]) : -INFINITY;
      mloc = fmaxf(mloc, ld[u]);
    }
    mloc = fmaxf(mloc, __shfl_xor(mloc, 1));
    mloc = fmaxf(mloc, __shfl_xor(mloc, 2));
    float rsum = 0.f;
    #pragma unroll
    for (int u = 0; u < 4; ++u) {
      const int t = g4*4 + u;
      float cv = 0.f;
      if (t <= sI) cv = (qk[u] * 0.125f) * __expf(ld[u] - mloc);
      csv[u] = cv;
      rsum += cv;
    }
    rsum += __shfl_xor(rsum, 1);
    rsum += __shfl_xor(rsum, 2);
    const float denom = fmaxf(fabsf(rsum), __expf(-mloc)) + 1e-6f;
    const float inv = 1.f / denom;
    #pragma unroll
    for (int u = 0; u < 4; ++u) csv[u] *= inv;
  }
  __syncthreads();   // B4 (all reads of s_q done; safe to overwrite with C)

  // C[h][s][t] aliased into s_q: index (h*16+s)*16 + t
  *(float4*)&s_q[((h*16 + sI)*16) + g4*4] = make_float4(csv[0], csv[1], csv[2], csv[3]);
  __syncthreads();   // B5

  // --- PV in channel layout: thread j owns v-column (regs) + C broadcast ---
  float o[16];
  {
    const float* cb0 = &s_q[(h*16)*16];
    #pragma unroll
    for (int s = 0; s < 16; ++s) {
      const float* crow = &cb0[s*16];
      float acc = 0.f;
      #pragma unroll
      for (int t4 = 0; t4 < 4; ++t4) {       // rows are zero beyond s
        const float4 c = *(const float4*)&crow[t4*4];
        acc = fmaf(c.x, vreg[t4*4+0], acc);
        acc = fmaf(c.y, vreg[t4*4+1], acc);
        acc = fmaf(c.z, vreg[t4*4+2], acc);
        acc = fmaf(c.w, vreg[t4*4+3], acc);
      }
      o[s] = acc;
    }
  }

  // --- LN over DH=64 (full-wave butterfly, two-pass) + epilogue, fused per s ---
  const float lnwj = lnw[j];
  const float skj  = skipw[j];
  #pragma unroll
  for (int s = 0; s < 16; ++s) {
    float sm = o[s];
    #pragma unroll
    for (int off = 1; off < 64; off <<= 1) sm += __shfl_xor(sm, off);
    const float mu = sm * (1.f/64.f);
    const float d = o[s] - mu;
    float sq = d*d;
    #pragma unroll
    for (int off = 1; off < 64; off <<= 1) sq += __shfl_xor(sq, off);
    const float rstd = rsqrtf(sq * (1.f/64.f) + 1e-5f);
    const int off_g = (rbase + s*1024)*256 + j;
    const float szv = sz_ws[off_g];
    h_ws[off_g] = (d*rstd*lnwj + skj*xc[s]) * szv;
  }
}

// ---------------------------------------------------------------------------
// Phase 3: down-projection GEMM + transpose-store (unchanged from R1).
// ---------------------------------------------------------------------------
__global__ __launch_bounds__(256, 4)
void down_gemm(const float* __restrict__ hws, const float* __restrict__ Wd,
               float* __restrict__ out)
{
  __shared__ float sA[32][132];
  __shared__ float sW[32][128];
  const int tid = threadIdx.x;
  const int th  = tid & 15;
  const int tj  = tid >> 4;
  const int hw0 = blockIdx.x * 128;
  const int bt  = blockIdx.z;
  const int b   = bt >> 4, t = bt & 15;

  float acc[8][8];
  #pragma unroll
  for (int i = 0; i < 8; ++i)
    #pragma unroll
    for (int k = 0; k < 8; ++k) acc[i][k] = 0.0f;

  const int rowbase = bt * 1024 + hw0;
  for (int k0 = 0; k0 < 256; k0 += 32) {
    #pragma unroll
    for (int r = 0; r < 4; ++r) {
      const int lin = r*256 + tid;
      const int hw  = lin >> 3;
      const int j4  = (lin & 7) * 4;
      const float4 v = *(const float4*)&hws[(rowbase + hw)*256 + k0 + j4];
      sA[j4+0][hw] = v.x;
      sA[j4+1][hw] = v.y;
      sA[j4+2][hw] = v.z;
      sA[j4+3][hw] = v.w;
    }
    #pragma unroll
    for (int r = 0; r < 4; ++r) {
      const int lin = r*256 + tid;
      const int row = lin >> 5;
      const int cv  = (lin & 31) * 4;
      *(float4*)&sW[row][cv] = *(const float4*)&Wd[(k0 + row)*128 + cv];
    }
    __syncthreads();
    #pragma unroll 4
    for (int kk = 0; kk < 32; ++kk) {
      const float4 a0 = *(const float4*)&sA[kk][th*4];
      const float4 a1 = *(const float4*)&sA[kk][64 + th*4];
      const float4 w0 = *(const float4*)&sW[kk][tj*4];
      const float4 w1 = *(const float4*)&sW[kk][64 + tj*4];
      const float av[8] = {a0.x,a0.y,a0.z,a0.w,a1.x,a1.y,a1.z,a1.w};
      const float wv[8] = {w0.x,w0.y,w0.z,w0.w,w1.x,w1.y,w1.z,w1.w};
      #pragma unroll
      for (int hh = 0; hh < 8; ++hh)
        #pragma unroll
        for (int cc = 0; cc < 8; ++cc)
          acc[hh][cc] += av[hh] * wv[cc];
    }
    __syncthreads();
  }

  #pragma unroll
  for (int jj = 0; jj < 8; ++jj) {
    const int c = (jj < 4) ? (tj*4 + jj) : (64 + tj*4 + jj - 4);
    const float4 v0 = make_float4(acc[0][jj], acc[1][jj], acc[2][jj], acc[3][jj]);
    const float4 v1 = make_float4(acc[4][jj], acc[5][jj], acc[6][jj], acc[7][jj]);
    const int obase = ((b*128 + c)*16 + t)*1024 + hw0;
    *(float4*)&out[obase + th*4]      = v0;
    *(float4*)&out[obase + 64 + th*4] = v1;
  }
}

// ---------------------------------------------------------------------------
extern "C" void kernel_launch(void* const* d_in, const int* in_sizes, int n_in,
                              void* d_out, int out_size, void* d_ws, size_t ws_size,
                              hipStream_t stream)
{
  const float* x      = (const float*)d_in[0];
  const float* Wup    = (const float*)d_in[1];
  const float* conv_w = (const float*)d_in[2];
  const float* conv_b = (const float*)d_in[3];
  const float* Wq     = (const float*)d_in[4];
  const float* Wk     = (const float*)d_in[5];
  const float* Wv     = (const float*)d_in[6];
  const float* igw    = (const float*)d_in[7];
  const float* igb    = (const float*)d_in[8];
  const float* fgw    = (const float*)d_in[9];
  const float* fgb    = (const float*)d_in[10];
  const float* lnw    = (const float*)d_in[11];
  const float* skipw  = (const float*)d_in[12];
  const float* Wd     = (const float*)d_in[13];
  float* out = (float*)d_out;

  float* xm = (float*)d_ws;
  float* sz = xm + 33554432;

  up_gemm<<<dim3(8, 4, 128), 256, 0, stream>>>(x, Wup, xm, sz);
  seq_kernel<<<8192, 256, 0, stream>>>(xm, sz, xm,
                                       conv_w, conv_b, Wq, Wk, Wv,
                                       igw, igb, fgw, fgb, lnw, skipw);
  down_gemm<<<dim3(8, 1, 128), 256, 0, stream>>>(xm, Wd, out);
}

// Round 3
// 520.674 us; speedup vs baseline: 1.8693x; 1.2794x over previous
//
#include <hip/hip_runtime.h>
#include <cmath>

// Problem constants: B=8, DIM=128, T=16, H*W=1024, INNER=256, UP2=512,
// NH=4, DH=64, K=4, Bx=8192 sequences, S=16.

typedef __attribute__((ext_vector_type(8))) short short8;
typedef __attribute__((ext_vector_type(4))) float f32x4;
typedef unsigned short ushort_t;

static __device__ __forceinline__ float dot4(float4 a, float4 b) {
  return a.x*b.x + a.y*b.y + a.z*b.z + a.w*b.w;
}
static __device__ __forceinline__ float siluf(float v) {
  return v / (1.0f + __expf(-v));
}
static __device__ __forceinline__ float logsigf(float v) {
  return fminf(v, 0.f) - log1pf(__expf(-fabsf(v)));
}
static __device__ __forceinline__ float sel4(float4 w, int idx) {
  float r = w.x;
  r = (idx == 1) ? w.y : r;
  r = (idx == 2) ? w.z : r;
  r = (idx == 3) ? w.w : r;
  return r;
}
static __device__ __forceinline__ ushort_t f2bf(float x) {   // RNE fp32->bf16
  unsigned u = __float_as_uint(x);
  return (ushort_t)((u + 0x7fffu + ((u >> 16) & 1u)) >> 16);
}
static __device__ __forceinline__ float bf2f(ushort_t h) {
  return __uint_as_float(((unsigned)h) << 16);
}

// ---------------------------------------------------------------------------
// Prep: transpose weights into fragment-major bf16 hi/lo.
// Wt[j][c] (512x128) from Wup[c][j]; Wdt[c][j] (128x256) from Wd[j][c].
// ---------------------------------------------------------------------------
__global__ __launch_bounds__(256)
void prep_w(const float* __restrict__ Wup, const float* __restrict__ Wd,
            ushort_t* __restrict__ wt_hi, ushort_t* __restrict__ wt_lo,
            ushort_t* __restrict__ wdt_hi, ushort_t* __restrict__ wdt_lo)
{
  const int g = blockIdx.x * 256 + threadIdx.x;
  if (g < 65536) {                      // g = c*512 + j
    const int c = g >> 9, j = g & 511;
    const float w = Wup[g];
    const ushort_t h = f2bf(w);
    wt_hi[j*128 + c] = h;
    wt_lo[j*128 + c] = f2bf(w - bf2f(h));
  } else {                              // g2 = j*128 + c
    const int g2 = g - 65536;
    const int j = g2 >> 7, c = g2 & 127;
    const float w = Wd[g2];
    const ushort_t h = f2bf(w);
    wdt_hi[c*256 + j] = h;
    wdt_lo[c*256 + j] = f2bf(w - bf2f(h));
  }
}

// ---------------------------------------------------------------------------
// Phase 1: up-projection via split-bf16 MFMA.
// D[m=hw][n=j] = sum_c x[c][hw] * Wup[c][j].  Block: 128 hw x 128 j, 4 waves
// as 2x2 of 64x64.  A (x) staged in LDS bf16 hi/lo; B fragments from global.
// j0<256 -> fp32 x_m; j0>=256 -> silu -> bf16 sz.
// ---------------------------------------------------------------------------
#define AS 72   // LDS row stride in bf16 (64 + 8 pad)

__global__ __launch_bounds__(256, 3)
void up_gemm(const float* __restrict__ x,
             const ushort_t* __restrict__ wt_hi, const ushort_t* __restrict__ wt_lo,
             float* __restrict__ xm, ushort_t* __restrict__ szb)
{
  __shared__ ushort_t sAhi[128*AS];
  __shared__ ushort_t sAlo[128*AS];

  const int tid = threadIdx.x;
  const int hw0 = blockIdx.x * 128;
  const int j0  = blockIdx.y * 128;
  const int bt  = blockIdx.z;
  const int b   = bt >> 4, t = bt & 15;

  const int wv = tid >> 6;
  const int wm = wv >> 1, wn = wv & 1;
  const int ln = tid & 63;
  const int lm = ln & 15;
  const int q  = ln >> 4;

  const int hwL = tid & 127;     // staging: hw within tile
  const int cg  = tid >> 7;      // staging: c sub-group (0/1)

  f32x4 acc[4][4];
  #pragma unroll
  for (int i = 0; i < 4; ++i)
    #pragma unroll
    for (int k = 0; k < 4; ++k) acc[i][k] = (f32x4){0.f, 0.f, 0.f, 0.f};

  for (int stage = 0; stage < 2; ++stage) {
    // --- stage A tile: 128 hw x 64 c, fp32 -> bf16 hi/lo ---
    #pragma unroll
    for (int p = 0; p < 8; ++p) {
      const int cl = p*8 + cg*4;                 // stage-local c base
      const int c  = stage*64 + cl;              // tile-global c
      const float* xp = &x[((b*128 + c)*16 + t)*1024 + hw0 + hwL];
      const float v0 = xp[0], v1 = xp[16384], v2 = xp[32768], v3 = xp[49152];
      const ushort_t h0 = f2bf(v0), h1 = f2bf(v1), h2 = f2bf(v2), h3 = f2bf(v3);
      const ushort_t l0 = f2bf(v0 - bf2f(h0)), l1 = f2bf(v1 - bf2f(h1));
      const ushort_t l2 = f2bf(v2 - bf2f(h2)), l3 = f2bf(v3 - bf2f(h3));
      *(ushort4*)&sAhi[hwL*AS + cl] = make_ushort4(h0, h1, h2, h3);
      *(ushort4*)&sAlo[hwL*AS + cl] = make_ushort4(l0, l1, l2, l3);
    }
    __syncthreads();

    #pragma unroll
    for (int s = 0; s < 2; ++s) {
      const int kc = s*32 + q*8;        // stage-local k for LDS
      const int kg = stage*64 + kc;     // global k (c) for B
      short8 bh[4], bl[4];
      #pragma unroll
      for (int nt = 0; nt < 4; ++nt) {
        const int jr = j0 + wn*64 + nt*16 + lm;
        bh[nt] = *(const short8*)&wt_hi[jr*128 + kg];
        bl[nt] = *(const short8*)&wt_lo[jr*128 + kg];
      }
      #pragma unroll
      for (int mt = 0; mt < 4; ++mt) {
        const int ao = (wm*64 + mt*16 + lm)*AS + kc;
        const short8 ah = *(const short8*)&sAhi[ao];
        const short8 al = *(const short8*)&sAlo[ao];
        #pragma unroll
        for (int nt = 0; nt < 4; ++nt) {
          acc[mt][nt] = __builtin_amdgcn_mfma_f32_16x16x32_bf16(ah, bh[nt], acc[mt][nt], 0, 0, 0);
          acc[mt][nt] = __builtin_amdgcn_mfma_f32_16x16x32_bf16(ah, bl[nt], acc[mt][nt], 0, 0, 0);
          acc[mt][nt] = __builtin_amdgcn_mfma_f32_16x16x32_bf16(al, bh[nt], acc[mt][nt], 0, 0, 0);
        }
      }
    }
    __syncthreads();
  }

  // --- epilogue: coalesced stores (16 consecutive j per 16 lanes) ---
  const bool isz = (j0 >= 256);
  #pragma unroll
  for (int mt = 0; mt < 4; ++mt) {
    #pragma unroll
    for (int nt = 0; nt < 4; ++nt) {
      const int jc = j0 + wn*64 + nt*16 + lm;
      #pragma unroll
      for (int r = 0; r < 4; ++r) {
        const int rowg = bt*1024 + hw0 + wm*64 + mt*16 + q*4 + r;
        const float v = acc[mt][nt][r];
        if (!isz) xm[rowg*256 + jc] = v;
        else      szb[rowg*256 + (jc - 256)] = f2bf(siluf(v));
      }
    }
  }
}

// ---------------------------------------------------------------------------
// Phase 2: per-sequence fused conv + headwise qkv + gates + mLSTM + LN + skip.
// Same as R2 except: sz is bf16; h_state written back (bf16) over the sz slot.
// ---------------------------------------------------------------------------
#define QR 264

__global__ __launch_bounds__(256, 3)
void seq_kernel(const float* __restrict__ xm_ws,
                ushort_t* szh,                    // silu(z) in, h_state out
                const float* __restrict__ conv_w, const float* __restrict__ conv_b,
                const float* __restrict__ Wq, const float* __restrict__ Wk,
                const float* __restrict__ Wv,
                const float* __restrict__ igw, const float* __restrict__ igb,
                const float* __restrict__ fgw, const float* __restrict__ fgb,
                const float* __restrict__ lnw, const float* __restrict__ skipw)
{
  __shared__ __align__(16) float s_q[16*QR];   // later aliased as C[4][16][16]
  __shared__ __align__(16) float s_k[16*QR];
  __shared__ __align__(16) float s_v[16*QR];
  __shared__ __align__(16) float s_ig[16*4];
  __shared__ __align__(16) float s_lf[16*4];
  __shared__ float s_lfc[17*4];

  const int tid = threadIdx.x;
  const int j   = tid;
  const int l2  = j & 3;
  const int seq = blockIdx.x;
  const int rbase = (seq >> 10) * 16384 + (seq & 1023);

  const float4 wq4 = *(const float4*)&Wq[j*4];
  const float4 wk4 = *(const float4*)&Wk[j*4];
  const float4 wv4 = *(const float4*)&Wv[j*4];
  float wqp[4], wkp[4], wvp[4];
  #pragma unroll
  for (int d = 0; d < 4; ++d) {
    const int idx = l2 ^ d;
    wqp[d] = sel4(wq4, idx);
    wkp[d] = sel4(wk4, idx);
    wvp[d] = sel4(wv4, idx);
  }
  const float cw0 = conv_w[j],     cw1 = conv_w[256+j];
  const float cw2 = conv_w[512+j], cw3 = conv_w[768+j];
  const float cb  = conv_b[j];

  float xc[16], vreg[16];
  float p1 = 0.f, p2 = 0.f, p3 = 0.f;
  #pragma unroll
  for (int t = 0; t < 16; ++t) {
    const float m = xm_ws[(rbase + t*1024)*256 + j];
    const float pre = cw0*p3 + cw1*p2 + cw2*p1 + cw3*m + cb;
    const float x = siluf(pre);
    xc[t] = x;
    p3 = p2; p2 = p1; p1 = m;
    const float x1 = __shfl_xor(x, 1), x2 = __shfl_xor(x, 2), x3 = __shfl_xor(x, 3);
    const float m1 = __shfl_xor(m, 1), m2 = __shfl_xor(m, 2), m3 = __shfl_xor(m, 3);
    const float qv = x*wqp[0] + x1*wqp[1] + x2*wqp[2] + x3*wqp[3];
    const float kv = x*wkp[0] + x1*wkp[1] + x2*wkp[2] + x3*wkp[3];
    const float vv = m*wvp[0] + m1*wvp[1] + m2*wvp[2] + m3*wvp[3];
    s_q[t*QR + j] = qv;
    s_k[t*QR + j] = kv;
    s_v[t*QR + j] = vv;
    vreg[t] = vv;
  }
  __syncthreads();

  {
    const int gt = tid >> 4, gp = tid & 15;
    float4 aig = make_float4(0.f,0.f,0.f,0.f);
    float4 afg = make_float4(0.f,0.f,0.f,0.f);
    const float* qrow = &s_q[gt*QR];
    const float* krow = &s_k[gt*QR];
    const float* vrow = &s_v[gt*QR];
    #pragma unroll
    for (int m = 0; m < 16; ++m) {
      const int ch = gp + (m << 4);
      const float y = qrow[ch];
      const float4 wi = *(const float4*)&igw[ch*4];
      const float4 wf = *(const float4*)&fgw[ch*4];
      aig.x = fmaf(y, wi.x, aig.x); aig.y = fmaf(y, wi.y, aig.y);
      aig.z = fmaf(y, wi.z, aig.z); aig.w = fmaf(y, wi.w, aig.w);
      afg.x = fmaf(y, wf.x, afg.x); afg.y = fmaf(y, wf.y, afg.y);
      afg.z = fmaf(y, wf.z, afg.z); afg.w = fmaf(y, wf.w, afg.w);
    }
    #pragma unroll
    for (int m = 0; m < 16; ++m) {
      const int ch = gp + (m << 4);
      const float y = krow[ch];
      const float4 wi = *(const float4*)&igw[(256+ch)*4];
      const float4 wf = *(const float4*)&fgw[(256+ch)*4];
      aig.x = fmaf(y, wi.x, aig.x); aig.y = fmaf(y, wi.y, aig.y);
      aig.z = fmaf(y, wi.z, aig.z); aig.w = fmaf(y, wi.w, aig.w);
      afg.x = fmaf(y, wf.x, afg.x); afg.y = fmaf(y, wf.y, afg.y);
      afg.z = fmaf(y, wf.z, afg.z); afg.w = fmaf(y, wf.w, afg.w);
    }
    #pragma unroll
    for (int m = 0; m < 16; ++m) {
      const int ch = gp + (m << 4);
      const float y = vrow[ch];
      const float4 wi = *(const float4*)&igw[(512+ch)*4];
      const float4 wf = *(const float4*)&fgw[(512+ch)*4];
      aig.x = fmaf(y, wi.x, aig.x); aig.y = fmaf(y, wi.y, aig.y);
      aig.z = fmaf(y, wi.z, aig.z); aig.w = fmaf(y, wi.w, aig.w);
      afg.x = fmaf(y, wf.x, afg.x); afg.y = fmaf(y, wf.y, afg.y);
      afg.z = fmaf(y, wf.z, afg.z); afg.w = fmaf(y, wf.w, afg.w);
    }
    #pragma unroll
    for (int off = 1; off < 16; off <<= 1) {
      aig.x += __shfl_xor(aig.x, off); aig.y += __shfl_xor(aig.y, off);
      aig.z += __shfl_xor(aig.z, off); aig.w += __shfl_xor(aig.w, off);
      afg.x += __shfl_xor(afg.x, off); afg.y += __shfl_xor(afg.y, off);
      afg.z += __shfl_xor(afg.z, off); afg.w += __shfl_xor(afg.w, off);
    }
    if (gp == 0) {
      const float4 ib = *(const float4*)&igb[0];
      const float4 fb = *(const float4*)&fgb[0];
      *(float4*)&s_ig[gt*4] = make_float4(aig.x+ib.x, aig.y+ib.y, aig.z+ib.z, aig.w+ib.w);
      *(float4*)&s_lf[gt*4] = make_float4(logsigf(afg.x+fb.x), logsigf(afg.y+fb.y),
                                          logsigf(afg.z+fb.z), logsigf(afg.w+fb.w));
    }
  }
  __syncthreads();
  if (tid < 4) {
    float run = 0.f;
    s_lfc[tid] = 0.f;
    #pragma unroll
    for (int t = 0; t < 16; ++t) { run += s_lf[t*4 + tid]; s_lfc[(t+1)*4 + tid] = run; }
  }
  __syncthreads();

  const int h    = tid >> 6;
  const int lane = tid & 63;
  const int sI   = lane >> 2;
  const int g4   = lane & 3;
  const int hb   = h * 64;

  float csv[4];
  {
    float qk[4] = {0.f, 0.f, 0.f, 0.f};
    #pragma unroll 4
    for (int d4 = 0; d4 < 16; ++d4) {
      const float4 qv = *(const float4*)&s_q[sI*QR + hb + d4*4];
      #pragma unroll
      for (int u = 0; u < 4; ++u) {
        const float4 kv = *(const float4*)&s_k[(g4*4+u)*QR + hb + d4*4];
        qk[u] += dot4(qv, kv);
      }
    }
    const float lfs = s_lfc[(sI+1)*4 + h];
    float ld[4];
    float mloc = -INFINITY;
    #pragma unroll
    for (int u = 0; u < 4; ++u) {
      const int t = g4*4 + u;
      ld[u] = (t <= sI) ? (lfs - s_lfc[(t+1)*4 + h] + s_ig[t*4 + h]) : -INFINITY;
      mloc = fmaxf(mloc, ld[u]);
    }
    mloc = fmaxf(mloc, __shfl_xor(mloc, 1));
    mloc = fmaxf(mloc, __shfl_xor(mloc, 2));
    float rsum = 0.f;
    #pragma unroll
    for (int u = 0; u < 4; ++u) {
      const int t = g4*4 + u;
      float cv = 0.f;
      if (t <= sI) cv = (qk[u] * 0.125f) * __expf(ld[u] - mloc);
      csv[u] = cv;
      rsum += cv;
    }
    rsum += __shfl_xor(rsum, 1);
    rsum += __shfl_xor(rsum, 2);
    const float denom = fmaxf(fabsf(rsum), __expf(-mloc)) + 1e-6f;
    const float inv = 1.f / denom;
    #pragma unroll
    for (int u = 0; u < 4; ++u) csv[u] *= inv;
  }
  __syncthreads();

  *(float4*)&s_q[((h*16 + sI)*16) + g4*4] = make_float4(csv[0], csv[1], csv[2], csv[3]);
  __syncthreads();

  float o[16];
  {
    const float* cb0 = &s_q[(h*16)*16];
    #pragma unroll
    for (int s = 0; s < 16; ++s) {
      const float* crow = &cb0[s*16];
      float acc = 0.f;
      #pragma unroll
      for (int t4 = 0; t4 < 4; ++t4) {
        const float4 c = *(const float4*)&crow[t4*4];
        acc = fmaf(c.x, vreg[t4*4+0], acc);
        acc = fmaf(c.y, vreg[t4*4+1], acc);
        acc = fmaf(c.z, vreg[t4*4+2], acc);
        acc = fmaf(c.w, vreg[t4*4+3], acc);
      }
      o[s] = acc;
    }
  }

  const float lnwj = lnw[j];
  const float skj  = skipw[j];
  #pragma unroll
  for (int s = 0; s < 16; ++s) {
    float sm = o[s];
    #pragma unroll
    for (int off = 1; off < 64; off <<= 1) sm += __shfl_xor(sm, off);
    const float mu = sm * (1.f/64.f);
    const float d = o[s] - mu;
    float sq = d*d;
    #pragma unroll
    for (int off = 1; off < 64; off <<= 1) sq += __shfl_xor(sq, off);
    const float rstd = rsqrtf(sq * (1.f/64.f) + 1e-5f);
    const int off_g = (rbase + s*1024)*256 + j;
    const float szv = bf2f(szh[off_g]);
    const float hs = (d*rstd*lnwj + skj*xc[s]) * szv;
    szh[off_g] = f2bf(hs);                // h_state (bf16) over the sz slot
  }
}

// ---------------------------------------------------------------------------
// Phase 3: down-projection, split-bf16 MFMA, no LDS.
// D[m=c][n=hw] = sum_j Wd[j][c] * h[hw][j].  A = Wdt hi/lo fragments (global),
// B = h already bf16 (2 MFMA per tile).  Coalesced store into [b][c][t][hw].
// ---------------------------------------------------------------------------
__global__ __launch_bounds__(256, 3)
void down_gemm(const ushort_t* __restrict__ hb,
               const ushort_t* __restrict__ wdt_hi, const ushort_t* __restrict__ wdt_lo,
               float* __restrict__ out)
{
  const int tid = threadIdx.x;
  const int hw0 = blockIdx.x * 128;
  const int bt  = blockIdx.z;
  const int bq  = bt >> 4, tq = bt & 15;
  const int rowbase = bt*1024 + hw0;

  const int wv = tid >> 6;
  const int wm = wv >> 1, wn = wv & 1;
  const int ln = tid & 63;
  const int lm = ln & 15;
  const int q  = ln >> 4;

  f32x4 acc[4][4];
  #pragma unroll
  for (int i = 0; i < 4; ++i)
    #pragma unroll
    for (int k = 0; k < 4; ++k) acc[i][k] = (f32x4){0.f, 0.f, 0.f, 0.f};

  #pragma unroll 2
  for (int kc = 0; kc < 256; kc += 32) {
    const int kq = kc + q*8;
    short8 ah[4], al[4];
    #pragma unroll
    for (int mt = 0; mt < 4; ++mt) {
      const int c = wm*64 + mt*16 + lm;
      ah[mt] = *(const short8*)&wdt_hi[c*256 + kq];
      al[mt] = *(const short8*)&wdt_lo[c*256 + kq];
    }
    #pragma unroll
    for (int nt = 0; nt < 4; ++nt) {
      const int n = wn*64 + nt*16 + lm;
      const short8 bf = *(const short8*)&hb[(rowbase + n)*256 + kq];
      #pragma unroll
      for (int mt = 0; mt < 4; ++mt) {
        acc[mt][nt] = __builtin_amdgcn_mfma_f32_16x16x32_bf16(ah[mt], bf, acc[mt][nt], 0, 0, 0);
        acc[mt][nt] = __builtin_amdgcn_mfma_f32_16x16x32_bf16(al[mt], bf, acc[mt][nt], 0, 0, 0);
      }
    }
  }

  #pragma unroll
  for (int mt = 0; mt < 4; ++mt) {
    #pragma unroll
    for (int nt = 0; nt < 4; ++nt) {
      const int hw = hw0 + wn*64 + nt*16 + lm;
      #pragma unroll
      for (int r = 0; r < 4; ++r) {
        const int c = wm*64 + mt*16 + q*4 + r;
        out[((bq*128 + c)*16 + tq)*1024 + hw] = acc[mt][nt][r];
      }
    }
  }
}

// ---------------------------------------------------------------------------
extern "C" void kernel_launch(void* const* d_in, const int* in_sizes, int n_in,
                              void* d_out, int out_size, void* d_ws, size_t ws_size,
                              hipStream_t stream)
{
  const float* x      = (const float*)d_in[0];
  const float* Wup    = (const float*)d_in[1];
  const float* conv_w = (const float*)d_in[2];
  const float* conv_b = (const float*)d_in[3];
  const float* Wq     = (const float*)d_in[4];
  const float* Wk     = (const float*)d_in[5];
  const float* Wv     = (const float*)d_in[6];
  const float* igw    = (const float*)d_in[7];
  const float* igb    = (const float*)d_in[8];
  const float* fgw    = (const float*)d_in[9];
  const float* fgb    = (const float*)d_in[10];
  const float* lnw    = (const float*)d_in[11];
  const float* skipw  = (const float*)d_in[12];
  const float* Wd     = (const float*)d_in[13];
  float* out = (float*)d_out;

  // ws layout: xm fp32 [131072][256] = 128 MB; szb bf16 [131072][256] = 64 MB
  // (silu(z) in, h_state out); then weight fragments (384 KB). Total ~192.4 MB.
  float*    xm     = (float*)d_ws;
  ushort_t* szb    = (ushort_t*)((char*)d_ws + 134217728);
  ushort_t* wt_hi  = (ushort_t*)((char*)d_ws + 201326592);
  ushort_t* wt_lo  = wt_hi + 65536;
  ushort_t* wdt_hi = wt_lo + 65536;
  ushort_t* wdt_lo = wdt_hi + 32768;

  prep_w<<<384, 256, 0, stream>>>(Wup, Wd, wt_hi, wt_lo, wdt_hi, wdt_lo);
  up_gemm<<<dim3(8, 4, 128), 256, 0, stream>>>(x, wt_hi, wt_lo, xm, szb);
  seq_kernel<<<8192, 256, 0, stream>>>(xm, szb,
                                       conv_w, conv_b, Wq, Wk, Wv,
                                       igw, igb, fgw, fgb, lnw, skipw);
  down_gemm<<<dim3(8, 1, 128), 256, 0, stream>>>(szb, wdt_hi, wdt_lo, out);
}

// Round 4
// 391.946 us; speedup vs baseline: 2.4833x; 1.3284x over previous
//
#include <hip/hip_runtime.h>
#include <cmath>

// Problem constants: B=8, DIM=128, T=16, H*W=1024, INNER=256, UP2=512,
// NH=4, DH=64, K=4, Bx=8192 sequences, S=16.

typedef __attribute__((ext_vector_type(8))) short short8;
typedef __attribute__((ext_vector_type(4))) short short4v;
typedef __attribute__((ext_vector_type(4))) float f32x4;
typedef unsigned short ushort_t;

static __device__ __forceinline__ float siluf(float v) {
  return v / (1.0f + __expf(-v));
}
static __device__ __forceinline__ float logsigf(float v) {
  return fminf(v, 0.f) - log1pf(__expf(-fabsf(v)));
}
static __device__ __forceinline__ float sel4(float4 w, int idx) {
  float r = w.x;
  r = (idx == 1) ? w.y : r;
  r = (idx == 2) ? w.z : r;
  r = (idx == 3) ? w.w : r;
  return r;
}
static __device__ __forceinline__ ushort_t f2bf(float x) {   // RNE fp32->bf16
  unsigned u = __float_as_uint(x);
  return (ushort_t)((u + 0x7fffu + ((u >> 16) & 1u)) >> 16);
}
static __device__ __forceinline__ float bf2f(ushort_t h) {
  return __uint_as_float(((unsigned)h) << 16);
}

// ---------------------------------------------------------------------------
// Prep: weight fragments.
//  wt_hi/lo [j][c]   (512x128)  from Wup[c][j]      (up GEMM B-operand)
//  wdt_hi/lo [c][j]  (128x256)  from Wd[j][c]       (down GEMM A-operand)
//  wgf [24][64][8]   bf16       gate-GEMM B-fragments: B[k=ch][n], n<4 = ig
//                    head n, 4<=n<8 = fg head n-4, n>=8 zero.
// ---------------------------------------------------------------------------
__global__ __launch_bounds__(256)
void prep_w(const float* __restrict__ Wup, const float* __restrict__ Wd,
            const float* __restrict__ igw, const float* __restrict__ fgw,
            ushort_t* __restrict__ wt_hi, ushort_t* __restrict__ wt_lo,
            ushort_t* __restrict__ wdt_hi, ushort_t* __restrict__ wdt_lo,
            ushort_t* __restrict__ wgf)
{
  const int g = blockIdx.x * 256 + threadIdx.x;
  if (g < 65536) {                      // g = c*512 + j
    const int c = g >> 9, j = g & 511;
    const float w = Wup[g];
    const ushort_t h = f2bf(w);
    wt_hi[j*128 + c] = h;
    wt_lo[j*128 + c] = f2bf(w - bf2f(h));
  } else if (g < 98304) {               // g2 = j*128 + c
    const int g2 = g - 65536;
    const int j = g2 >> 7, c = g2 & 127;
    const float w = Wd[g2];
    const ushort_t h = f2bf(w);
    wdt_hi[c*256 + j] = h;
    wdt_lo[c*256 + j] = f2bf(w - bf2f(h));
  } else if (g < 110592) {              // gate fragments
    const int e = g - 98304;            // e = kc*512 + lane*8 + i
    const int kc = e >> 9;
    const int lane = (e >> 3) & 63;
    const int i = e & 7;
    const int n = lane & 15;
    const int kq = kc*32 + (lane >> 4)*8 + i;
    float val = 0.f;
    if (n < 4)      val = igw[kq*4 + n];
    else if (n < 8) val = fgw[kq*4 + (n - 4)];
    wgf[e] = f2bf(val);
  }
}

// ---------------------------------------------------------------------------
// Phase 1: up-projection via split-bf16 MFMA (as R3), but x_m stored bf16.
// ---------------------------------------------------------------------------
#define AS 72   // LDS row stride in bf16 (64 + 8 pad)

__global__ __launch_bounds__(256, 3)
void up_gemm(const float* __restrict__ x,
             const ushort_t* __restrict__ wt_hi, const ushort_t* __restrict__ wt_lo,
             ushort_t* __restrict__ xmb, ushort_t* __restrict__ szb)
{
  __shared__ ushort_t sAhi[128*AS];
  __shared__ ushort_t sAlo[128*AS];

  const int tid = threadIdx.x;
  const int hw0 = blockIdx.x * 128;
  const int j0  = blockIdx.y * 128;
  const int bt  = blockIdx.z;
  const int b   = bt >> 4, t = bt & 15;

  const int wv = tid >> 6;
  const int wm = wv >> 1, wn = wv & 1;
  const int ln = tid & 63;
  const int lm = ln & 15;
  const int q  = ln >> 4;

  const int hwL = tid & 127;
  const int cg  = tid >> 7;

  f32x4 acc[4][4];
  #pragma unroll
  for (int i = 0; i < 4; ++i)
    #pragma unroll
    for (int k = 0; k < 4; ++k) acc[i][k] = (f32x4){0.f, 0.f, 0.f, 0.f};

  for (int stage = 0; stage < 2; ++stage) {
    #pragma unroll
    for (int p = 0; p < 8; ++p) {
      const int cl = p*8 + cg*4;
      const int c  = stage*64 + cl;
      const float* xp = &x[((b*128 + c)*16 + t)*1024 + hw0 + hwL];
      const float v0 = xp[0], v1 = xp[16384], v2 = xp[32768], v3 = xp[49152];
      const ushort_t h0 = f2bf(v0), h1 = f2bf(v1), h2 = f2bf(v2), h3 = f2bf(v3);
      const ushort_t l0 = f2bf(v0 - bf2f(h0)), l1 = f2bf(v1 - bf2f(h1));
      const ushort_t l2 = f2bf(v2 - bf2f(h2)), l3 = f2bf(v3 - bf2f(h3));
      *(ushort4*)&sAhi[hwL*AS + cl] = make_ushort4(h0, h1, h2, h3);
      *(ushort4*)&sAlo[hwL*AS + cl] = make_ushort4(l0, l1, l2, l3);
    }
    __syncthreads();

    #pragma unroll
    for (int s = 0; s < 2; ++s) {
      const int kc = s*32 + q*8;
      const int kg = stage*64 + kc;
      short8 bh[4], bl[4];
      #pragma unroll
      for (int nt = 0; nt < 4; ++nt) {
        const int jr = j0 + wn*64 + nt*16 + lm;
        bh[nt] = *(const short8*)&wt_hi[jr*128 + kg];
        bl[nt] = *(const short8*)&wt_lo[jr*128 + kg];
      }
      #pragma unroll
      for (int mt = 0; mt < 4; ++mt) {
        const int ao = (wm*64 + mt*16 + lm)*AS + kc;
        const short8 ah = *(const short8*)&sAhi[ao];
        const short8 al = *(const short8*)&sAlo[ao];
        #pragma unroll
        for (int nt = 0; nt < 4; ++nt) {
          acc[mt][nt] = __builtin_amdgcn_mfma_f32_16x16x32_bf16(ah, bh[nt], acc[mt][nt], 0, 0, 0);
          acc[mt][nt] = __builtin_amdgcn_mfma_f32_16x16x32_bf16(ah, bl[nt], acc[mt][nt], 0, 0, 0);
          acc[mt][nt] = __builtin_amdgcn_mfma_f32_16x16x32_bf16(al, bh[nt], acc[mt][nt], 0, 0, 0);
        }
      }
    }
    __syncthreads();
  }

  const bool isz = (j0 >= 256);
  #pragma unroll
  for (int mt = 0; mt < 4; ++mt) {
    #pragma unroll
    for (int nt = 0; nt < 4; ++nt) {
      const int jc = j0 + wn*64 + nt*16 + lm;
      #pragma unroll
      for (int r = 0; r < 4; ++r) {
        const int rowg = bt*1024 + hw0 + wm*64 + mt*16 + q*4 + r;
        const float v = acc[mt][nt][r];
        if (!isz) xmb[rowg*256 + jc] = f2bf(v);
        else      szb[rowg*256 + (jc - 256)] = f2bf(siluf(v));
      }
    }
  }
}

// ---------------------------------------------------------------------------
// Phase 2: fused conv + qkv + gates + mLSTM + LN + skip, MFMA-ized.
// LDS ~40 KB -> 4 blocks/CU. MFMA fragment layouts (verified by R3 GEMM):
//   A-frag: lane holds A[m=lane&15][k=(lane>>4)*8 + i], i=0..7 (contig bf16)
//   B-frag: lane holds B[k=(lane>>4)*8 + i][n=lane&15]
//   C/D:    lane holds D[row=(lane>>4)*4 + r][col=lane&15]
// ---------------------------------------------------------------------------
#define SQ 264    // q/k/v row stride (bf16): 528 B -> 2-way banks (free), 16B-aligned rows
#define SXC 260   // xc row stride (bf16), scalar access only

__global__ __launch_bounds__(256, 4)
void seq_kernel(const ushort_t* __restrict__ xm_ws,
                ushort_t* szh,                    // silu(z) in, h_state out
                const float* __restrict__ conv_w, const float* __restrict__ conv_b,
                const float* __restrict__ Wq, const float* __restrict__ Wk,
                const float* __restrict__ Wv,
                const ushort_t* __restrict__ wgf,
                const float* __restrict__ igb, const float* __restrict__ fgb,
                const float* __restrict__ lnw, const float* __restrict__ skipw)
{
  __shared__ __align__(16) ushort_t q_lds[16*SQ];
  __shared__ __align__(16) ushort_t k_lds[16*SQ];
  __shared__ __align__(16) ushort_t v_lds[16*SQ];
  __shared__ __align__(16) ushort_t xc_lds[16*SXC];
  __shared__ __align__(16) ushort_t p_lds[4*16*36];   // P[h][s][t], stride 36
  __shared__ __align__(16) float s_gpart[512];        // [w][t][8]; later aliased s_lfc[17][4]
  __shared__ float s_ig[64];                          // [t][h]
  __shared__ float s_lf[64];                          // [t][h]

  const int tid = threadIdx.x;
  const int j   = tid;
  const int l2  = j & 3;
  const int seq = blockIdx.x;
  const int rbase = (seq >> 10) * 16384 + (seq & 1023);

  const int w    = tid >> 6;      // wave = head
  const int ln   = tid & 63;
  const int g    = ln >> 4;       // 16-lane group
  const int lc   = ln & 15;       // lane-in-group (MFMA col / A-row)
  const int hb2  = w * 64;

  // --- weights for headwise qkv (lane-permuted for quad shuffles) ---
  const float4 wq4 = *(const float4*)&Wq[j*4];
  const float4 wk4 = *(const float4*)&Wk[j*4];
  const float4 wv4 = *(const float4*)&Wv[j*4];
  float wqp[4], wkp[4], wvp[4];
  #pragma unroll
  for (int d = 0; d < 4; ++d) {
    const int idx = l2 ^ d;
    wqp[d] = sel4(wq4, idx);
    wkp[d] = sel4(wk4, idx);
    wvp[d] = sel4(wv4, idx);
  }
  const float cw0 = conv_w[j],     cw1 = conv_w[256+j];
  const float cw2 = conv_w[512+j], cw3 = conv_w[768+j];
  const float cb  = conv_b[j];

  // --- Phase A: conv + silu + headwise q,k,v ; write bf16 to LDS ---
  float p1 = 0.f, p2 = 0.f, p3 = 0.f;
  #pragma unroll
  for (int t = 0; t < 16; ++t) {
    const float m = bf2f(xm_ws[(rbase + t*1024)*256 + j]);
    const float pre = cw0*p3 + cw1*p2 + cw2*p1 + cw3*m + cb;
    const float x = siluf(pre);
    p3 = p2; p2 = p1; p1 = m;
    const float x1 = __shfl_xor(x, 1), x2 = __shfl_xor(x, 2), x3 = __shfl_xor(x, 3);
    const float m1 = __shfl_xor(m, 1), m2 = __shfl_xor(m, 2), m3 = __shfl_xor(m, 3);
    const float qv = x*wqp[0] + x1*wqp[1] + x2*wqp[2] + x3*wqp[3];
    const float kv = x*wkp[0] + x1*wkp[1] + x2*wkp[2] + x3*wkp[3];
    const float vv = m*wvp[0] + m1*wvp[1] + m2*wvp[2] + m3*wvp[3];
    q_lds [t*SQ  + j] = f2bf(qv);
    k_lds [t*SQ  + j] = f2bf(kv);
    v_lds [t*SQ  + j] = f2bf(vv);
    xc_lds[t*SXC + j] = f2bf(x);
  }
  __syncthreads();   // B1

  // --- Gates via MFMA: Y[16t x 768] * W[768 x 8(+8 pad)], K-split by wave ---
  f32x4 gacc = (f32x4){0.f, 0.f, 0.f, 0.f};
  #pragma unroll
  for (int c6 = 0; c6 < 6; ++c6) {
    const int kc = w*6 + c6;                        // global K-chunk (wave-uniform)
    const ushort_t* yb = (kc < 8) ? q_lds : (kc < 16) ? k_lds : v_lds;
    const int klocal = (kc & 7)*32;
    const short8 ya = *(const short8*)&yb[lc*SQ + klocal + g*8];
    const short8 wb = *(const short8*)&wgf[(kc*64 + ln)*8];
    gacc = __builtin_amdgcn_mfma_f32_16x16x32_bf16(ya, wb, gacc, 0, 0, 0);
  }
  // QK^T via MFMA (needs only q,k of own head; independent of gates)
  f32x4 qkacc = (f32x4){0.f, 0.f, 0.f, 0.f};
  {
    const short8 qa0 = *(const short8*)&q_lds[lc*SQ + hb2 + g*8];
    const short8 qa1 = *(const short8*)&q_lds[lc*SQ + hb2 + 32 + g*8];
    const short8 kb0 = *(const short8*)&k_lds[lc*SQ + hb2 + g*8];
    const short8 kb1 = *(const short8*)&k_lds[lc*SQ + hb2 + 32 + g*8];
    qkacc = __builtin_amdgcn_mfma_f32_16x16x32_bf16(qa0, kb0, qkacc, 0, 0, 0);
    qkacc = __builtin_amdgcn_mfma_f32_16x16x32_bf16(qa1, kb1, qkacc, 0, 0, 0);
  }
  // store gate partials (cols 0..7 valid)
  if (lc < 8) {
    #pragma unroll
    for (int r = 0; r < 4; ++r)
      s_gpart[w*128 + (g*4 + r)*8 + lc] = gacc[r];
  }
  __syncthreads();   // B2

  // --- finalize gates: sum 4 wave-partials, bias, logsig ---
  if (tid < 128) {
    const int t = tid >> 3, n = tid & 7;
    const float s = s_gpart[t*8+n] + s_gpart[128 + t*8+n]
                  + s_gpart[256 + t*8+n] + s_gpart[384 + t*8+n];
    if (n < 4) s_ig[t*4 + n] = s + igb[n];
    else       s_lf[t*4 + (n-4)] = logsigf(s + fgb[n-4]);
  }
  __syncthreads();   // B3

  float* s_lfc = s_gpart;        // alias (gpart dead): [17][4]
  if (tid < 4) {
    float run = 0.f;
    s_lfc[tid] = 0.f;
    #pragma unroll
    for (int t = 0; t < 16; ++t) { run += s_lf[t*4 + tid]; s_lfc[(t+1)*4 + tid] = run; }
  }
  __syncthreads();   // B4

  // --- decay + normalizer in C-layout: lane holds rows s=g*4+r, col t=lc ---
  {
    const int tcol = lc;
    const float lfc_t1 = s_lfc[(tcol+1)*4 + w];
    const float igt    = s_ig[tcol*4 + w];
    float ld[4], mloc[4];
    #pragma unroll
    for (int r = 0; r < 4; ++r) {
      const int s = g*4 + r;
      const float lfs = s_lfc[(s+1)*4 + w];
      ld[r] = (tcol <= s) ? (lfs - lfc_t1 + igt) : -INFINITY;
      mloc[r] = ld[r];
    }
    #pragma unroll
    for (int off = 1; off < 16; off <<= 1) {
      #pragma unroll
      for (int r = 0; r < 4; ++r) mloc[r] = fmaxf(mloc[r], __shfl_xor(mloc[r], off));
    }
    float cs[4], rsum[4];
    #pragma unroll
    for (int r = 0; r < 4; ++r) {
      const int s = g*4 + r;
      cs[r] = (tcol <= s) ? (qkacc[r] * 0.125f) * __expf(ld[r] - mloc[r]) : 0.f;
      rsum[r] = cs[r];
    }
    #pragma unroll
    for (int off = 1; off < 16; off <<= 1) {
      #pragma unroll
      for (int r = 0; r < 4; ++r) rsum[r] += __shfl_xor(rsum[r], off);
    }
    #pragma unroll
    for (int r = 0; r < 4; ++r) {
      const float denom = fmaxf(fabsf(rsum[r]), __expf(-mloc[r])) + 1e-6f;
      const float pv = cs[r] / denom;
      p_lds[(w*16 + g*4 + r)*36 + tcol] = f2bf(pv);
    }
  }
  __syncthreads();   // B5

  // --- PV via MFMA: O[16s x 64d] = P[16 x 32pad] x V[32pad x 64] ---
  f32x4 oacc[4];
  #pragma unroll
  for (int c = 0; c < 4; ++c) oacc[c] = (f32x4){0.f, 0.f, 0.f, 0.f};
  {
    const int tb = g*8;
    short8 pa = (short8){0,0,0,0,0,0,0,0};
    if (tb < 16) {
      const short4v plo = *(const short4v*)&p_lds[(w*16 + lc)*36 + tb];
      const short4v phi = *(const short4v*)&p_lds[(w*16 + lc)*36 + tb + 4];
      pa[0]=plo[0]; pa[1]=plo[1]; pa[2]=plo[2]; pa[3]=plo[3];
      pa[4]=phi[0]; pa[5]=phi[1]; pa[6]=phi[2]; pa[7]=phi[3];
    }
    #pragma unroll
    for (int c = 0; c < 4; ++c) {
      short8 vb;
      #pragma unroll
      for (int i = 0; i < 8; ++i)
        vb[i] = (short)v_lds[((tb + i) & 15)*SQ + hb2 + c*16 + lc];  // garbage ok when tb>=16 (A=0)
      oacc[c] = __builtin_amdgcn_mfma_f32_16x16x32_bf16(pa, vb, oacc[c], 0, 0, 0);
    }
  }

  // --- LN over DH=64 + epilogue; lane holds O[s=g*4+r][d=c*16+lc] ---
  float lnc[4], skc[4];
  #pragma unroll
  for (int c = 0; c < 4; ++c) {
    const int ch = hb2 + c*16 + lc;
    lnc[c] = lnw[ch];
    skc[c] = skipw[ch];
  }
  #pragma unroll
  for (int r = 0; r < 4; ++r) {
    const int s = g*4 + r;
    float tot = oacc[0][r] + oacc[1][r] + oacc[2][r] + oacc[3][r];
    #pragma unroll
    for (int off = 1; off < 16; off <<= 1) tot += __shfl_xor(tot, off);
    const float mu = tot * (1.f/64.f);
    float var = 0.f;
    #pragma unroll
    for (int c = 0; c < 4; ++c) { const float d = oacc[c][r] - mu; var += d*d; }
    #pragma unroll
    for (int off = 1; off < 16; off <<= 1) var += __shfl_xor(var, off);
    const float rstd = rsqrtf(var * (1.f/64.f) + 1e-5f);
    #pragma unroll
    for (int c = 0; c < 4; ++c) {
      const int ch = hb2 + c*16 + lc;
      const float hn = (oacc[c][r] - mu) * rstd * lnc[c];
      const float xcv = bf2f(xc_lds[s*SXC + ch]);
      const long long off_g = (long long)(rbase + s*1024)*256 + ch;
      const float szv = bf2f(szh[off_g]);
      szh[off_g] = f2bf((hn + skc[c]*xcv) * szv);
    }
  }
}

// ---------------------------------------------------------------------------
// Phase 3: down-projection, split-bf16 MFMA (unchanged from R3).
// ---------------------------------------------------------------------------
__global__ __launch_bounds__(256, 3)
void down_gemm(const ushort_t* __restrict__ hb,
               const ushort_t* __restrict__ wdt_hi, const ushort_t* __restrict__ wdt_lo,
               float* __restrict__ out)
{
  const int tid = threadIdx.x;
  const int hw0 = blockIdx.x * 128;
  const int bt  = blockIdx.z;
  const int bq  = bt >> 4, tq = bt & 15;
  const int rowbase = bt*1024 + hw0;

  const int wv = tid >> 6;
  const int wm = wv >> 1, wn = wv & 1;
  const int ln = tid & 63;
  const int lm = ln & 15;
  const int q  = ln >> 4;

  f32x4 acc[4][4];
  #pragma unroll
  for (int i = 0; i < 4; ++i)
    #pragma unroll
    for (int k = 0; k < 4; ++k) acc[i][k] = (f32x4){0.f, 0.f, 0.f, 0.f};

  #pragma unroll 2
  for (int kc = 0; kc < 256; kc += 32) {
    const int kq = kc + q*8;
    short8 ah[4], al[4];
    #pragma unroll
    for (int mt = 0; mt < 4; ++mt) {
      const int c = wm*64 + mt*16 + lm;
      ah[mt] = *(const short8*)&wdt_hi[c*256 + kq];
      al[mt] = *(const short8*)&wdt_lo[c*256 + kq];
    }
    #pragma unroll
    for (int nt = 0; nt < 4; ++nt) {
      const int n = wn*64 + nt*16 + lm;
      const short8 bf = *(const short8*)&hb[(rowbase + n)*256 + kq];
      #pragma unroll
      for (int mt = 0; mt < 4; ++mt) {
        acc[mt][nt] = __builtin_amdgcn_mfma_f32_16x16x32_bf16(ah[mt], bf, acc[mt][nt], 0, 0, 0);
        acc[mt][nt] = __builtin_amdgcn_mfma_f32_16x16x32_bf16(al[mt], bf, acc[mt][nt], 0, 0, 0);
      }
    }
  }

  #pragma unroll
  for (int mt = 0; mt < 4; ++mt) {
    #pragma unroll
    for (int nt = 0; nt < 4; ++nt) {
      const int hw = hw0 + wn*64 + nt*16 + lm;
      #pragma unroll
      for (int r = 0; r < 4; ++r) {
        const int c = wm*64 + mt*16 + q*4 + r;
        out[((bq*128 + c)*16 + tq)*1024 + hw] = acc[mt][nt][r];
      }
    }
  }
}

// ---------------------------------------------------------------------------
extern "C" void kernel_launch(void* const* d_in, const int* in_sizes, int n_in,
                              void* d_out, int out_size, void* d_ws, size_t ws_size,
                              hipStream_t stream)
{
  const float* x      = (const float*)d_in[0];
  const float* Wup    = (const float*)d_in[1];
  const float* conv_w = (const float*)d_in[2];
  const float* conv_b = (const float*)d_in[3];
  const float* Wq     = (const float*)d_in[4];
  const float* Wk     = (const float*)d_in[5];
  const float* Wv     = (const float*)d_in[6];
  const float* igw    = (const float*)d_in[7];
  const float* igb    = (const float*)d_in[8];
  const float* fgw    = (const float*)d_in[9];
  const float* fgb    = (const float*)d_in[10];
  const float* lnw    = (const float*)d_in[11];
  const float* skipw  = (const float*)d_in[12];
  const float* Wd     = (const float*)d_in[13];
  float* out = (float*)d_out;

  // ws layout: xmb bf16 [131072][256] = 64 MB; szb bf16 = 64 MB (silu(z) in,
  // h_state out); then weight fragments (~0.4 MB).
  ushort_t* xmb    = (ushort_t*)d_ws;
  ushort_t* szb    = xmb + 33554432;
  ushort_t* wt_hi  = (ushort_t*)((char*)d_ws + 134217728);
  ushort_t* wt_lo  = wt_hi + 65536;
  ushort_t* wdt_hi = wt_lo + 65536;
  ushort_t* wdt_lo = wdt_hi + 32768;
  ushort_t* wgf    = wdt_lo + 32768;    // 24*64*8 = 12288 bf16

  prep_w<<<432, 256, 0, stream>>>(Wup, Wd, igw, fgw,
                                  wt_hi, wt_lo, wdt_hi, wdt_lo, wgf);
  up_gemm<<<dim3(8, 4, 128), 256, 0, stream>>>(x, wt_hi, wt_lo, xmb, szb);
  seq_kernel<<<8192, 256, 0, stream>>>(xmb, szb,
                                       conv_w, conv_b, Wq, Wk, Wv,
                                       wgf, igb, fgb, lnw, skipw);
  down_gemm<<<dim3(8, 1, 128), 256, 0, stream>>>(szb, wdt_hi, wdt_lo, out);
}